// Round 1
// baseline (334.501 us; speedup 1.0000x reference)
//
#include <hip/hip_runtime.h>

// GroupSort over channel pairs:
//   out[:,2k]   = xe - relu(xe - xo)   (== pairwise min, computed ref-exactly)
//   out[:,2k+1] = xo + relu(xe - xo)   (== pairwise max)
// x: (B=32, C=512, H=56, W=56) fp32 contiguous. Channel plane = 56*56 = 3136
// floats = 784 float4s. Even/odd channels of a pair are adjacent planes.
//
// Memory-bound: 411 MB total traffic -> ~65 us floor at 6.3 TB/s.

#define HW4 784                      // float4s per channel plane
#define TOTAL4 6422528               // B * (C/2) * HW / 4 = 32*256*784

__global__ __launch_bounds__(256) void groupsort_kernel(
    const float4* __restrict__ in, float4* __restrict__ out) {
    unsigned int i = blockIdx.x * 256u + threadIdx.x;
    if (i >= TOTAL4) return;
    unsigned int pair = i / HW4;                 // which (b, k) pair
    unsigned int hw   = i - pair * HW4;          // float4 offset within plane
    unsigned int base = pair * (2u * HW4) + hw;  // even-channel float4 index

    float4 e = in[base];
    float4 o = in[base + HW4];

    float4 zl, eo, oo;
    zl.x = fmaxf(e.x - o.x, 0.0f);
    zl.y = fmaxf(e.y - o.y, 0.0f);
    zl.z = fmaxf(e.z - o.z, 0.0f);
    zl.w = fmaxf(e.w - o.w, 0.0f);
    eo.x = e.x - zl.x;  oo.x = o.x + zl.x;
    eo.y = e.y - zl.y;  oo.y = o.y + zl.y;
    eo.z = e.z - zl.z;  oo.z = o.z + zl.z;
    eo.w = e.w - zl.w;  oo.w = o.w + zl.w;

    out[base]       = eo;
    out[base + HW4] = oo;
}

extern "C" void kernel_launch(void* const* d_in, const int* in_sizes, int n_in,
                              void* d_out, int out_size, void* d_ws, size_t ws_size,
                              hipStream_t stream) {
    const float4* x = (const float4*)d_in[0];
    float4* out = (float4*)d_out;
    const int blocks = (TOTAL4 + 255) / 256;  // 25088, exact
    groupsort_kernel<<<blocks, 256, 0, stream>>>(x, out);
}

// Round 2
// 321.305 us; speedup vs baseline: 1.0411x; 1.0411x over previous
//
#include <hip/hip_runtime.h>

// GroupSort over channel pairs (B=32, C=512, H=56, W=56 fp32):
//   out[:,2k]   = xe - relu(xe - xo)   (pairwise min, ref-exact arithmetic)
//   out[:,2k+1] = xo + relu(xe - xo)   (pairwise max)
// Channel plane = 3136 floats = 784 float4s; pair channels are adjacent planes.
// Pure streaming: 205.5 MB in + 205.5 MB out (> L3) -> HBM-bound, ~68 us floor.
// Nontemporal hints: every line is touched exactly once, keep it out of L2/L3.

#define HW4 784u                     // float4s per channel plane
#define TOTAL4 6422528u              // 32 * 256 * 784  (== 25088 * 256 exactly)

typedef float v4 __attribute__((ext_vector_type(4)));

__global__ __launch_bounds__(256) void groupsort_kernel(
    const v4* __restrict__ in, v4* __restrict__ out) {
    unsigned int i = blockIdx.x * 256u + threadIdx.x;   // grid is exact, no guard
    unsigned int pair = i / HW4;                 // magic-mul, cheap
    unsigned int hw   = i - pair * HW4;
    unsigned int base = pair * (2u * HW4) + hw;  // even-channel float4 index

    v4 e = __builtin_nontemporal_load(in + base);
    v4 o = __builtin_nontemporal_load(in + base + HW4);

    v4 d = e - o;
    v4 z;
    z.x = fmaxf(d.x, 0.0f);
    z.y = fmaxf(d.y, 0.0f);
    z.z = fmaxf(d.z, 0.0f);
    z.w = fmaxf(d.w, 0.0f);
    v4 eo = e - z;
    v4 oo = o + z;

    __builtin_nontemporal_store(eo, out + base);
    __builtin_nontemporal_store(oo, out + base + HW4);
}

extern "C" void kernel_launch(void* const* d_in, const int* in_sizes, int n_in,
                              void* d_out, int out_size, void* d_ws, size_t ws_size,
                              hipStream_t stream) {
    const v4* x = (const v4*)d_in[0];
    v4* out = (v4*)d_out;
    groupsort_kernel<<<TOTAL4 / 256u, 256, 0, stream>>>(x, out);
}